// Round 1
// baseline (127.023 us; speedup 1.0000x reference)
//
#include <hip/hip_runtime.h>

#define BB  2
#define TT  2048
#define DIN 128
#define NS  64
#define NC  128
#define CL  16
#define L2E 1.4426950408889634f

#if __has_builtin(__builtin_amdgcn_exp2f)
__device__ __forceinline__ float fexp2(float x) { return __builtin_amdgcn_exp2f(x); }
#else
__device__ __forceinline__ float fexp2(float x) { return exp2f(x); }
#endif

// ---- K0: a2[n] = sum_m A[n,m] * log2(e) ----
__global__ void k_a2(const float* __restrict__ A, float* __restrict__ a2) {
  int n = threadIdx.x;
  float s = 0.f;
  for (int m = 0; m < NS; ++m) s += A[n * NS + m];
  a2[n] = s * L2E;
}

// ---- K1: xp = x @ W^T ; split into xcin / delta(sigmoid) / B / C ----
__global__ __launch_bounds__(128) void k_proj(
    const float* __restrict__ x, const float* __restrict__ W,
    float* __restrict__ xcin, float* __restrict__ delta,
    float* __restrict__ Bb, float* __restrict__ Cb) {
  __shared__ float xs[128 * 68];
  int tile = blockIdx.x, rg = blockIdx.y, tid = threadIdx.x;
  int base = tile * 128;  // flat (b*T+t) start
  for (int i = tid; i < 128 * 64; i += 128)
    xs[(i >> 6) * 68 + (i & 63)] = x[base * 64 + i];
  __syncthreads();
  float xr[64];
#pragma unroll
  for (int k = 0; k < 64; ++k) xr[k] = xs[tid * 68 + k];
  int bt = base + tid;
  for (int rr = 0; rr < 64; ++rr) {
    int r = rg * 64 + rr;
    const float* __restrict__ wrow = W + r * 64;
    float acc = 0.f;
#pragma unroll
    for (int k = 0; k < 64; ++k) acc = fmaf(xr[k], wrow[k], acc);
    if (r < 128) {
      xcin[bt * DIN + r] = acc;
    } else if (r < 256) {
      delta[bt * DIN + (r - 128)] = 1.f / (1.f + fexp2(-acc * L2E));  // sigmoid
    } else if (r < 320) {
      Bb[bt * NS + (r - 256)] = acc;
    } else {
      Cb[bt * NS + (r - 320)] = acc;
    }
  }
}

// ---- K2: causal depthwise conv(k=4) + dx = delta*xconv ; ybase = D*xconv ----
__global__ void k_conv(const float* __restrict__ xcin, const float* __restrict__ delta,
                       const float* __restrict__ cw, const float* __restrict__ cb,
                       const float* __restrict__ Dp,
                       float* __restrict__ dx, float* __restrict__ ybase) {
  int idx = blockIdx.x * 256 + threadIdx.x;   // over B*T*DIN
  int d = idx & (DIN - 1);
  int bt = idx >> 7;
  int t = bt & (TT - 1);
  float acc = cb[d];
#pragma unroll
  for (int j = 0; j < 4; ++j) {
    int ts = t - 3 + j;
    float v = (ts >= 0) ? xcin[(bt - 3 + j) * DIN + d] : 0.f;
    acc = fmaf(cw[d * 4 + j], v, acc);
  }
  dx[idx] = delta[idx] * acc;
  ybase[idx] = Dp[d] * acc;
}

// ---- K3: phase-1 local chunk scans (both dirs), store chunk-final state + delta-sum ----
__global__ __launch_bounds__(128) void k_scan1(
    const float* __restrict__ delta, const float* __restrict__ dx,
    const float* __restrict__ Bb, const float* __restrict__ a2g,
    float* __restrict__ hend, float* __restrict__ sumd) {
  int c = blockIdx.x, b = blockIdx.y, dir = blockIdx.z;
  int d = threadIdx.x;
  float a2r[NS];
#pragma unroll
  for (int n = 0; n < NS; ++n) a2r[n] = a2g[n];
  float h[NS];
#pragma unroll
  for (int n = 0; n < NS; ++n) h[n] = 0.f;
  float sd = 0.f;
  int t0 = c * CL;
  for (int i = 0; i < CL; ++i) {
    int t = dir ? (t0 + CL - 1 - i) : (t0 + i);
    int e = b * TT + t;
    float de = delta[e * DIN + d];
    float dxv = dx[e * DIN + d];
    sd += de;
    const float* __restrict__ Brow = Bb + e * NS;
#pragma unroll
    for (int n = 0; n < NS; ++n) {
      float eb = fexp2(de * a2r[n]);
      h[n] = fmaf(eb, h[n], dxv * Brow[n]);
    }
  }
  float* __restrict__ hp = hend + ((dir * NC + c) * BB + b) * NS * DIN;
#pragma unroll
  for (int n = 0; n < NS; ++n) hp[n * DIN + d] = h[n];
  if (dir == 0) sumd[(c * BB + b) * DIN + d] = sd;
}

// ---- K4: sequential cross-chunk combine -> chunk initial states (hin) ----
__global__ void k_comb(const float* __restrict__ hend, float* __restrict__ hin,
                       const float* __restrict__ sumd, const float* __restrict__ a2g) {
  int idx = blockIdx.x * 256 + threadIdx.x;   // over B*2*NS*DIN = 32768
  int d = idx & (DIN - 1);
  int n = (idx >> 7) & (NS - 1);
  int bd = idx >> 13;
  int b = bd >> 1, dir = bd & 1;
  float a2n = a2g[n];
  float carry = 0.f;
#pragma unroll 8
  for (int ci = 0; ci < NC; ++ci) {
    int c = dir ? (NC - 1 - ci) : ci;
    float e = fexp2(a2n * sumd[(c * BB + b) * DIN + d]);
    int base = ((dir * NC + c) * BB + b) * NS * DIN + n * DIN + d;
    float tmp = hend[base];
    hin[base] = carry;
    carry = fmaf(e, carry, tmp);
  }
}

// ---- K5: phase-3 full local scans with correct init, produce y per dir ----
__global__ __launch_bounds__(128) void k_scan2(
    const float* __restrict__ delta, const float* __restrict__ dx,
    const float* __restrict__ Bb, const float* __restrict__ Cb,
    const float* __restrict__ a2g, const float* __restrict__ hin,
    float* __restrict__ yd) {
  int c = blockIdx.x, b = blockIdx.y, dir = blockIdx.z;
  int d = threadIdx.x;
  float a2r[NS];
#pragma unroll
  for (int n = 0; n < NS; ++n) a2r[n] = a2g[n];
  float h[NS];
  const float* __restrict__ hp = hin + ((dir * NC + c) * BB + b) * NS * DIN;
#pragma unroll
  for (int n = 0; n < NS; ++n) h[n] = hp[n * DIN + d];
  int t0 = c * CL;
  for (int i = 0; i < CL; ++i) {
    int t = dir ? (t0 + CL - 1 - i) : (t0 + i);
    int e = b * TT + t;
    float de = delta[e * DIN + d];
    float dxv = dx[e * DIN + d];
    const float* __restrict__ Brow = Bb + e * NS;
    const float* __restrict__ Crow = Cb + e * NS;
    float y0 = 0.f, y1 = 0.f, y2 = 0.f, y3 = 0.f;
#pragma unroll
    for (int n = 0; n < NS; n += 4) {
      float e0 = fexp2(de * a2r[n + 0]); h[n + 0] = fmaf(e0, h[n + 0], dxv * Brow[n + 0]); y0 = fmaf(h[n + 0], Crow[n + 0], y0);
      float e1 = fexp2(de * a2r[n + 1]); h[n + 1] = fmaf(e1, h[n + 1], dxv * Brow[n + 1]); y1 = fmaf(h[n + 1], Crow[n + 1], y1);
      float e2 = fexp2(de * a2r[n + 2]); h[n + 2] = fmaf(e2, h[n + 2], dxv * Brow[n + 2]); y2 = fmaf(h[n + 2], Crow[n + 2], y2);
      float e3 = fexp2(de * a2r[n + 3]); h[n + 3] = fmaf(e3, h[n + 3], dxv * Brow[n + 3]); y3 = fmaf(h[n + 3], Crow[n + 3], y3);
    }
    yd[dir * (BB * TT * DIN) + e * DIN + d] = (y0 + y1) + (y2 + y3);
  }
}

// ---- K6: out = y_fwd + y_rev + D*xconv ----
__global__ void k_final(const float* __restrict__ yd, const float* __restrict__ ybase,
                        float* __restrict__ out) {
  int i = blockIdx.x * 256 + threadIdx.x;
  out[i] = yd[i] + yd[BB * TT * DIN + i] + ybase[i];
}

extern "C" void kernel_launch(void* const* d_in, const int* in_sizes, int n_in,
                              void* d_out, int out_size, void* d_ws, size_t ws_size,
                              hipStream_t stream) {
  const float* x  = (const float*)d_in[0];
  const float* W  = (const float*)d_in[1];
  const float* cw = (const float*)d_in[2];
  const float* cb = (const float*)d_in[3];
  const float* A  = (const float*)d_in[4];
  const float* Dp = (const float*)d_in[5];
  float* out = (float*)d_out;

  float* ws = (float*)d_ws;
  const int BTD = BB * TT * DIN;  // 524288
  const int BTN = BB * TT * NS;   // 262144
  float* xcin  = ws;
  float* delta = xcin + BTD;
  float* dx    = delta + BTD;
  float* ybase = dx + BTD;
  float* Bbuf  = ybase + BTD;
  float* Cbuf  = Bbuf + BTN;
  float* a2    = Cbuf + BTN;
  float* sumd  = a2 + 128;
  float* hend  = sumd + NC * BB * DIN;
  float* hin   = hend + 2 * NC * BB * NS * DIN;
  float* yd    = hin + 2 * NC * BB * NS * DIN;
  // total ws use: ~46.1 MB

  hipLaunchKernelGGL(k_a2,   dim3(1), dim3(64), 0, stream, A, a2);
  hipLaunchKernelGGL(k_proj, dim3(BB * TT / 128, 6), dim3(128), 0, stream, x, W, xcin, delta, Bbuf, Cbuf);
  hipLaunchKernelGGL(k_conv, dim3(BTD / 256), dim3(256), 0, stream, xcin, delta, cw, cb, Dp, dx, ybase);
  hipLaunchKernelGGL(k_scan1, dim3(NC, BB, 2), dim3(128), 0, stream, delta, dx, Bbuf, a2, hend, sumd);
  hipLaunchKernelGGL(k_comb, dim3(BB * 2 * NS * DIN / 256), dim3(256), 0, stream, hend, hin, sumd, a2);
  hipLaunchKernelGGL(k_scan2, dim3(NC, BB, 2), dim3(128), 0, stream, delta, dx, Bbuf, Cbuf, a2, hin, yd);
  hipLaunchKernelGGL(k_final, dim3(BTD / 256), dim3(256), 0, stream, yd, ybase, out);
}

// Round 2
// 92.929 us; speedup vs baseline: 1.3669x; 1.3669x over previous
//
#include <hip/hip_runtime.h>

#define BB  2
#define TT  2048
#define DIN 128
#define NS  64
#define NC  128
#define CL  16
#define L2E 1.4426950408889634f

#if __has_builtin(__builtin_amdgcn_exp2f)
__device__ __forceinline__ float fexp2(float x) { return __builtin_amdgcn_exp2f(x); }
#else
__device__ __forceinline__ float fexp2(float x) { return exp2f(x); }
#endif

// ---- K1: xp = x @ W^T ; split into xcin / delta(sigmoid) / B / C ----
__global__ __launch_bounds__(128) void k_proj(
    const float* __restrict__ x, const float* __restrict__ W,
    float* __restrict__ xcin, float* __restrict__ delta,
    float* __restrict__ Bb, float* __restrict__ Cb) {
  __shared__ float xs[128 * 65];
  int tile = blockIdx.x, rg = blockIdx.y, tid = threadIdx.x;
  int base = tile * 128;  // flat (b*T+t) start
  const float4* __restrict__ x4 = (const float4*)(x + (size_t)base * 64);
  for (int i = tid; i < 128 * 16; i += 128) {
    float4 v = x4[i];
    int row = i >> 4, c4 = (i & 15) * 4;
    xs[row * 65 + c4 + 0] = v.x;
    xs[row * 65 + c4 + 1] = v.y;
    xs[row * 65 + c4 + 2] = v.z;
    xs[row * 65 + c4 + 3] = v.w;
  }
  __syncthreads();
  float xr[64];
#pragma unroll
  for (int k = 0; k < 64; ++k) xr[k] = xs[tid * 65 + k];
  int bt = base + tid;
  for (int rr = 0; rr < 32; ++rr) {
    int r = rg * 32 + rr;
    const float* __restrict__ wrow = W + r * 64;
    float a0 = 0.f, a1 = 0.f, a2 = 0.f, a3 = 0.f;
#pragma unroll
    for (int k = 0; k < 64; k += 4) {
      a0 = fmaf(xr[k + 0], wrow[k + 0], a0);
      a1 = fmaf(xr[k + 1], wrow[k + 1], a1);
      a2 = fmaf(xr[k + 2], wrow[k + 2], a2);
      a3 = fmaf(xr[k + 3], wrow[k + 3], a3);
    }
    float acc = (a0 + a1) + (a2 + a3);
    if (r < 128) {
      xcin[(size_t)bt * DIN + r] = acc;
    } else if (r < 256) {
      delta[(size_t)bt * DIN + (r - 128)] = 1.f / (1.f + fexp2(-acc * L2E));
    } else if (r < 320) {
      Bb[(size_t)bt * NS + (r - 256)] = acc;
    } else {
      Cb[(size_t)bt * NS + (r - 320)] = acc;
    }
  }
}

// ---- K2: phase-1 local chunk scans (both dirs, conv fused), store hend + sumd ----
__global__ __launch_bounds__(512) void k_scan1(
    const float* __restrict__ xcin, const float* __restrict__ delta,
    const float* __restrict__ Bb, const float* __restrict__ A,
    const float* __restrict__ cw, const float* __restrict__ cb,
    float* __restrict__ hend, float* __restrict__ sumd) {
  __shared__ float a2s[NS];
  int c = blockIdx.x;
  int b = blockIdx.y >> 1, dir = blockIdx.y & 1;
  int tid = threadIdx.x;
  int d = tid & 127;
  int grp = __builtin_amdgcn_readfirstlane(tid >> 7);
  if (tid < NS) {
    float s = 0.f;
#pragma unroll
    for (int m = 0; m < NS; ++m) s += A[tid * NS + m];
    a2s[tid] = s * L2E;
  }
  float cw0 = cw[d * 4 + 0], cw1 = cw[d * 4 + 1], cw2 = cw[d * 4 + 2], cw3 = cw[d * 4 + 3];
  float cbd = cb[d];
  __syncthreads();
  int nb = grp * 16;
  float a2r[16];
#pragma unroll
  for (int j = 0; j < 16; ++j) a2r[j] = a2s[nb + j];
  float h[16];
#pragma unroll
  for (int j = 0; j < 16; ++j) h[j] = 0.f;
  int t0 = c * CL;
  const float* __restrict__ xcB = xcin + (size_t)b * TT * DIN + d;
  const float* __restrict__ deB = delta + (size_t)b * TT * DIN + d;
  const float* __restrict__ BbB = Bb + (size_t)b * TT * NS + nb;
  float sd = 0.f;
  float w0, w1, w2, w3;
  if (dir == 0) {
    int t = t0;
    w0 = (t - 3 >= 0) ? xcB[(t - 3) * DIN] : 0.f;
    w1 = (t - 2 >= 0) ? xcB[(t - 2) * DIN] : 0.f;
    w2 = (t - 1 >= 0) ? xcB[(t - 1) * DIN] : 0.f;
    w3 = xcB[t * DIN];
    for (int i = 0; i < CL; ++i) {
      float xconv = fmaf(cw0, w0, fmaf(cw1, w1, fmaf(cw2, w2, fmaf(cw3, w3, cbd))));
      float de = deB[t * DIN];
      float dxv = de * xconv;
      sd += de;
      const float* __restrict__ Brow = BbB + t * NS;
#pragma unroll
      for (int j = 0; j < 16; ++j) {
        float eb = fexp2(de * a2r[j]);
        h[j] = fmaf(eb, h[j], dxv * Brow[j]);
      }
      if (i < CL - 1) { ++t; w0 = w1; w1 = w2; w2 = w3; w3 = xcB[t * DIN]; }
    }
  } else {
    int t = t0 + CL - 1;
    w3 = xcB[t * DIN];
    w2 = xcB[(t - 1) * DIN];
    w1 = xcB[(t - 2) * DIN];
    w0 = xcB[(t - 3) * DIN];
    for (int i = 0; i < CL; ++i) {
      float xconv = fmaf(cw0, w0, fmaf(cw1, w1, fmaf(cw2, w2, fmaf(cw3, w3, cbd))));
      float de = deB[t * DIN];
      float dxv = de * xconv;
      sd += de;
      const float* __restrict__ Brow = BbB + t * NS;
#pragma unroll
      for (int j = 0; j < 16; ++j) {
        float eb = fexp2(de * a2r[j]);
        h[j] = fmaf(eb, h[j], dxv * Brow[j]);
      }
      if (i < CL - 1) { --t; w3 = w2; w2 = w1; w1 = w0; w0 = (t - 3 >= 0) ? xcB[(t - 3) * DIN] : 0.f; }
    }
  }
  float* __restrict__ hp = hend + (((size_t)(dir * NC + c) * BB + b) * NS + nb) * DIN + d;
#pragma unroll
  for (int j = 0; j < 16; ++j) hp[j * DIN] = h[j];
  if (dir == 0 && grp == 0) sumd[(c * BB + b) * DIN + d] = sd;
}

// ---- K3: sequential cross-chunk combine -> chunk initial states (hin) ----
__global__ void k_comb(const float* __restrict__ hend, float* __restrict__ hin,
                       const float* __restrict__ sumd, const float* __restrict__ A) {
  int idx = blockIdx.x * 256 + threadIdx.x;   // over B*2*NS*DIN = 32768
  int d = idx & (DIN - 1);
  int n = __builtin_amdgcn_readfirstlane((idx >> 7) & (NS - 1));
  int bd = idx >> 13;
  int b = bd >> 1, dir = bd & 1;
  float s = 0.f;
#pragma unroll
  for (int m = 0; m < NS; ++m) s += A[n * NS + m];
  float a2n = s * L2E;
  float carry = 0.f;
#pragma unroll 8
  for (int ci = 0; ci < NC; ++ci) {
    int c = dir ? (NC - 1 - ci) : ci;
    float e = fexp2(a2n * sumd[(c * BB + b) * DIN + d]);
    size_t base = ((size_t)(dir * NC + c) * BB + b) * NS * DIN + n * DIN + d;
    float tmp = hend[base];
    hin[base] = carry;
    carry = fmaf(e, carry, tmp);
  }
}

// ---- K4: phase-3 full scans with init, conv fused, y reduce + atomic out ----
__global__ __launch_bounds__(512) void k_scan2(
    const float* __restrict__ xcin, const float* __restrict__ delta,
    const float* __restrict__ Bb, const float* __restrict__ Cb,
    const float* __restrict__ A, const float* __restrict__ cw,
    const float* __restrict__ cb, const float* __restrict__ Dp,
    const float* __restrict__ hin, float* __restrict__ out) {
  __shared__ float a2s[NS];
  __shared__ float yred[4][CL][DIN];   // 32 KB
  int c = blockIdx.x;
  int b = blockIdx.y >> 1, dir = blockIdx.y & 1;
  int tid = threadIdx.x;
  int d = tid & 127;
  int grp = __builtin_amdgcn_readfirstlane(tid >> 7);
  if (tid < NS) {
    float s = 0.f;
#pragma unroll
    for (int m = 0; m < NS; ++m) s += A[tid * NS + m];
    a2s[tid] = s * L2E;
  }
  float cw0 = cw[d * 4 + 0], cw1 = cw[d * 4 + 1], cw2 = cw[d * 4 + 2], cw3 = cw[d * 4 + 3];
  float cbd = cb[d];
  float Dd = Dp[d];
  __syncthreads();
  int nb = grp * 16;
  float a2r[16];
#pragma unroll
  for (int j = 0; j < 16; ++j) a2r[j] = a2s[nb + j];
  float h[16];
  const float* __restrict__ hp = hin + (((size_t)(dir * NC + c) * BB + b) * NS + nb) * DIN + d;
#pragma unroll
  for (int j = 0; j < 16; ++j) h[j] = hp[j * DIN];
  int t0 = c * CL;
  const float* __restrict__ xcB = xcin + (size_t)b * TT * DIN + d;
  const float* __restrict__ deB = delta + (size_t)b * TT * DIN + d;
  const float* __restrict__ BbB = Bb + (size_t)b * TT * NS + nb;
  const float* __restrict__ CbB = Cb + (size_t)b * TT * NS + nb;
  float yp[CL];
  float w0, w1, w2, w3;
  bool addD = (grp == 0) && (dir == 0);
  if (dir == 0) {
    int t = t0;
    w0 = (t - 3 >= 0) ? xcB[(t - 3) * DIN] : 0.f;
    w1 = (t - 2 >= 0) ? xcB[(t - 2) * DIN] : 0.f;
    w2 = (t - 1 >= 0) ? xcB[(t - 1) * DIN] : 0.f;
    w3 = xcB[t * DIN];
    for (int i = 0; i < CL; ++i) {
      float xconv = fmaf(cw0, w0, fmaf(cw1, w1, fmaf(cw2, w2, fmaf(cw3, w3, cbd))));
      float de = deB[t * DIN];
      float dxv = de * xconv;
      const float* __restrict__ Brow = BbB + t * NS;
      const float* __restrict__ Crow = CbB + t * NS;
      float y0 = 0.f, y1 = 0.f, y2 = 0.f, y3 = 0.f;
#pragma unroll
      for (int j = 0; j < 16; j += 4) {
        float e0 = fexp2(de * a2r[j + 0]); h[j + 0] = fmaf(e0, h[j + 0], dxv * Brow[j + 0]); y0 = fmaf(h[j + 0], Crow[j + 0], y0);
        float e1 = fexp2(de * a2r[j + 1]); h[j + 1] = fmaf(e1, h[j + 1], dxv * Brow[j + 1]); y1 = fmaf(h[j + 1], Crow[j + 1], y1);
        float e2 = fexp2(de * a2r[j + 2]); h[j + 2] = fmaf(e2, h[j + 2], dxv * Brow[j + 2]); y2 = fmaf(h[j + 2], Crow[j + 2], y2);
        float e3 = fexp2(de * a2r[j + 3]); h[j + 3] = fmaf(e3, h[j + 3], dxv * Brow[j + 3]); y3 = fmaf(h[j + 3], Crow[j + 3], y3);
      }
      float yv = (y0 + y1) + (y2 + y3);
      if (addD) yv = fmaf(Dd, xconv, yv);
      yp[i] = yv;
      if (i < CL - 1) { ++t; w0 = w1; w1 = w2; w2 = w3; w3 = xcB[t * DIN]; }
    }
  } else {
    int t = t0 + CL - 1;
    w3 = xcB[t * DIN];
    w2 = xcB[(t - 1) * DIN];
    w1 = xcB[(t - 2) * DIN];
    w0 = xcB[(t - 3) * DIN];
    for (int i = 0; i < CL; ++i) {
      float xconv = fmaf(cw0, w0, fmaf(cw1, w1, fmaf(cw2, w2, fmaf(cw3, w3, cbd))));
      float de = deB[t * DIN];
      float dxv = de * xconv;
      const float* __restrict__ Brow = BbB + t * NS;
      const float* __restrict__ Crow = CbB + t * NS;
      float y0 = 0.f, y1 = 0.f, y2 = 0.f, y3 = 0.f;
#pragma unroll
      for (int j = 0; j < 16; j += 4) {
        float e0 = fexp2(de * a2r[j + 0]); h[j + 0] = fmaf(e0, h[j + 0], dxv * Brow[j + 0]); y0 = fmaf(h[j + 0], Crow[j + 0], y0);
        float e1 = fexp2(de * a2r[j + 1]); h[j + 1] = fmaf(e1, h[j + 1], dxv * Brow[j + 1]); y1 = fmaf(h[j + 1], Crow[j + 1], y1);
        float e2 = fexp2(de * a2r[j + 2]); h[j + 2] = fmaf(e2, h[j + 2], dxv * Brow[j + 2]); y2 = fmaf(h[j + 2], Crow[j + 2], y2);
        float e3 = fexp2(de * a2r[j + 3]); h[j + 3] = fmaf(e3, h[j + 3], dxv * Brow[j + 3]); y3 = fmaf(h[j + 3], Crow[j + 3], y3);
      }
      float yv = (y0 + y1) + (y2 + y3);
      yp[i] = yv;
      if (i < CL - 1) { --t; w3 = w2; w2 = w1; w1 = w0; w0 = (t - 3 >= 0) ? xcB[(t - 3) * DIN] : 0.f; }
    }
  }
#pragma unroll
  for (int i = 0; i < CL; ++i) yred[grp][i][d] = yp[i];
  __syncthreads();
#pragma unroll
  for (int k = 0; k < 4; ++k) {
    int p = k * 512 + tid;
    int i = p >> 7, d2 = p & 127;
    float s = (yred[0][i][d2] + yred[1][i][d2]) + (yred[2][i][d2] + yred[3][i][d2]);
    int t = dir ? (t0 + CL - 1 - i) : (t0 + i);
    unsafeAtomicAdd(&out[((size_t)b * TT + t) * DIN + d2], s);
  }
}

extern "C" void kernel_launch(void* const* d_in, const int* in_sizes, int n_in,
                              void* d_out, int out_size, void* d_ws, size_t ws_size,
                              hipStream_t stream) {
  const float* x  = (const float*)d_in[0];
  const float* W  = (const float*)d_in[1];
  const float* cw = (const float*)d_in[2];
  const float* cb = (const float*)d_in[3];
  const float* A  = (const float*)d_in[4];
  const float* Dp = (const float*)d_in[5];
  float* out = (float*)d_out;

  float* ws = (float*)d_ws;
  const int BTD = BB * TT * DIN;  // 524288
  const int BTN = BB * TT * NS;   // 262144
  float* xcin  = ws;
  float* delta = xcin + BTD;
  float* Bbuf  = delta + BTD;
  float* Cbuf  = Bbuf + BTN;
  float* sumd  = Cbuf + BTN;
  float* hend  = sumd + NC * BB * DIN;
  float* hin   = hend + 2 * NC * BB * NS * DIN;
  // total ws use: ~40 MB

  hipMemsetAsync(d_out, 0, (size_t)BTD * sizeof(float), stream);
  hipLaunchKernelGGL(k_proj,  dim3(BB * TT / 128, 12), dim3(128), 0, stream, x, W, xcin, delta, Bbuf, Cbuf);
  hipLaunchKernelGGL(k_scan1, dim3(NC, BB * 2), dim3(512), 0, stream, xcin, delta, Bbuf, A, cw, cb, hend, sumd);
  hipLaunchKernelGGL(k_comb,  dim3(BB * 2 * NS * DIN / 256), dim3(256), 0, stream, hend, hin, sumd, A);
  hipLaunchKernelGGL(k_scan2, dim3(NC, BB * 2), dim3(512), 0, stream, xcin, delta, Bbuf, Cbuf, A, cw, cb, Dp, hin, out);
}